// Round 1
// 762.618 us; speedup vs baseline: 1.0743x; 1.0743x over previous
//
#include <hip/hip_runtime.h>
#include <math.h>

#define NPTS 4096
#define DIM 64
#define NM ((size_t)NPTS * (size_t)NPTS)
#define LOGW (-8.317766166719343f)   // -log(4096)
#define NEGINF (-__builtin_inff())

typedef __bf16 bf16x8 __attribute__((ext_vector_type(8)));
typedef float f32x4 __attribute__((ext_vector_type(4)));
typedef _Float16 half8 __attribute__((ext_vector_type(8)));

static __device__ __forceinline__ f32x4 mfma16(bf16x8 a, bf16x8 b, f32x4 c) {
  return __builtin_amdgcn_mfma_f32_16x16x32_bf16(a, b, c, 0, 0, 0);
}

// ---------------------------------------------------------------------------
// Normalize rows to unit L2 norm and split into bf16 hi/lo pairs
// (v = hi + lo with |lo| <= 2^-9 |v| -> split-bf16 GEMM gives ~fp32 accuracy).
// One wave per row; grid 2048 x 256 covers 8192 rows (x then y).
// ---------------------------------------------------------------------------
__global__ __launch_bounds__(256) void norm_split_kernel(
    const float* __restrict__ x, const float* __restrict__ y,
    __bf16* __restrict__ xh, __bf16* __restrict__ xl,
    __bf16* __restrict__ yh, __bf16* __restrict__ yl) {
  int row  = blockIdx.x * 4 + (threadIdx.x >> 6);
  int lane = threadIdx.x & 63;
  const float* src; __bf16 *dh, *dl;
  if (row < NPTS) {
    src = x + (size_t)row * DIM; dh = xh + (size_t)row * DIM; dl = xl + (size_t)row * DIM;
  } else {
    int r = row - NPTS;
    src = y + (size_t)r * DIM; dh = yh + (size_t)r * DIM; dl = yl + (size_t)r * DIM;
  }
  float v = src[lane];
  float s = v * v;
  #pragma unroll
  for (int o = 32; o; o >>= 1) s += __shfl_xor(s, o, 64);
  v *= 1.0f / sqrtf(s);
  __bf16 h = (__bf16)v;
  __bf16 l = (__bf16)(v - (float)h);
  dh[lane] = h;
  dl[lane] = l;
}

// ---------------------------------------------------------------------------
// Cost matrices via split-bf16 MFMA: C = max(1 - A.B^T, 0), stored fp16.
// blockIdx.z: 0 -> Cxy (x,y), 1 -> Cyx (y,x), 2 -> Cxx, 3 -> Cyy.
// 64x64 tile / block, 4 waves; wave w does rows [w*16, w*16+16), 4 col-tiles.
// dot = hi.hi + lo.hi + hi.lo  (lo.lo ~ 2^-18, dropped). 6 MFMA per 16x16 tile.
// A-frag: lane L holds A[m = L&15][k = (L>>4)*8 + j]; B identical (B^T GEMM).
// C/D: col = L&15, row = (L>>4)*4 + reg.
// NEW: results staged through LDS (row stride 72 fp16 = 144 B, keeps 16B
// alignment + spreads banks), then written out as fully-coalesced 16B chunks
// (8 lanes cover a 128B line). Old path was 2B scalar stores at 8KB row
// stride -> 32B partial-line segments -> 826 GB/s effective write BW.
// ---------------------------------------------------------------------------
__global__ __launch_bounds__(256) void cost_mfma_kernel(
    const __bf16* __restrict__ xh, const __bf16* __restrict__ xl,
    const __bf16* __restrict__ yh, const __bf16* __restrict__ yl,
    _Float16* __restrict__ Cw) {
  __shared__ _Float16 tile[64][72];   // 9216 B
  int mat = blockIdx.z;
  const __bf16 *Ah, *Al, *Bh, *Bl;
  if (mat == 0)      { Ah = xh; Al = xl; Bh = yh; Bl = yl; }
  else if (mat == 1) { Ah = yh; Al = yl; Bh = xh; Bl = xl; }
  else if (mat == 2) { Ah = xh; Al = xl; Bh = xh; Bl = xl; }
  else               { Ah = yh; Al = yl; Bh = yh; Bl = yl; }
  _Float16* Cout = Cw + (size_t)mat * NM;

  int i0 = blockIdx.y * 64, j0 = blockIdx.x * 64;
  int wave = threadIdx.x >> 6, L = threadIdx.x & 63;
  int mrow = L & 15, quad = L >> 4;

  size_t abase = (size_t)(i0 + wave * 16 + mrow) * DIM + quad * 8;
  bf16x8 ah0 = *(const bf16x8*)(Ah + abase);
  bf16x8 ah1 = *(const bf16x8*)(Ah + abase + 32);
  bf16x8 al0 = *(const bf16x8*)(Al + abase);
  bf16x8 al1 = *(const bf16x8*)(Al + abase + 32);

  #pragma unroll
  for (int ct = 0; ct < 4; ++ct) {
    size_t bbase = (size_t)(j0 + ct * 16 + mrow) * DIM + quad * 8;
    bf16x8 bh0 = *(const bf16x8*)(Bh + bbase);
    bf16x8 bh1 = *(const bf16x8*)(Bh + bbase + 32);
    bf16x8 bl0 = *(const bf16x8*)(Bl + bbase);
    bf16x8 bl1 = *(const bf16x8*)(Bl + bbase + 32);
    f32x4 acc = {0.0f, 0.0f, 0.0f, 0.0f};
    acc = mfma16(ah0, bh0, acc);
    acc = mfma16(ah1, bh1, acc);
    acc = mfma16(al0, bh0, acc);
    acc = mfma16(al1, bh1, acc);
    acc = mfma16(ah0, bl0, acc);
    acc = mfma16(ah1, bl1, acc);
    #pragma unroll
    for (int q = 0; q < 4; ++q)
      tile[wave * 16 + quad * 4 + q][ct * 16 + mrow] =
          (_Float16)fmaxf(1.0f - acc[q], 0.0f);
  }
  __syncthreads();
  // write-out: 64 rows x 8 chunks of 8 fp16 (16B); 8 consecutive lanes = 128B
  #pragma unroll
  for (int rep = 0; rep < 2; ++rep) {
    int id = threadIdx.x + rep * 256;
    int r = id >> 3, ck = (id & 7) * 8;
    half8 v = *(const half8*)&tile[r][ck];
    *(half8*)(Cout + (size_t)(i0 + r) * NPTS + (j0 + ck)) = v;
  }
}

// ---------------------------------------------------------------------------
// One sweep: 4 row-softmins over the 4 fp16 matrices, with the 0.5-average
// update fused (ping-pong potOld -> potNew; no separate update kernel).
//   mat 0: Cxy rows  -> ft_ba, h from g_ab  (reads pot[1], writes pot[0])
//   mat 1: Cyx rows  -> gt_ab, h from f_ba  (reads pot[0], writes pot[1])
//   mat 2: Cxx rows  -> ft_aa, h from f_aa  (reads/writes pot[2])
//   mat 3: Cyy rows  -> gt_bb, h from g_bb  (reads/writes pot[3])
// Blocked-max online logsumexp: per 8-element chunk compute chunk max via a
// 7-fmax tree (no serial dep), merge with running max ONCE, rescale s ONCE.
// 9 exps / 8 elems (was 16) and the per-element m->s serial chain is gone.
// Grid 4096 blocks (4 mats x 1024), 4 rows/block (one wave per row).
// ---------------------------------------------------------------------------
__global__ __launch_bounds__(256) void pass_kernel(
    const _Float16* __restrict__ Cw,
    const float* __restrict__ potOld, float* __restrict__ potNew,
    float inv_eps, float eps, int use_pot, int avg) {
  int blk  = blockIdx.x;
  int mat  = blk >> 10;
  int row  = (blk & 1023) * 4 + (threadIdx.x >> 6);
  int lane = threadIdx.x & 63;
  const _Float16* Crow = Cw + (size_t)mat * NM + (size_t)row * NPTS;
  int ridx = (mat == 0) ? 1 : ((mat == 1) ? 0 : mat);
  const float* pot = potOld + (size_t)ridx * NPTS;
  float nie = -inv_eps;

  float m = NEGINF, s = 0.0f;
  #pragma unroll 2
  for (int t = 0; t < 8; ++t) {
    int j = lane * 8 + t * 512;
    half8 c8 = *(const half8*)(Crow + j);
    float tv0, tv1, tv2, tv3, tv4, tv5, tv6, tv7;
    if (use_pot) {
      float4 pa = *(const float4*)(pot + j);
      float4 pb = *(const float4*)(pot + j + 4);
      tv0 = fmaf((float)c8[0], nie, fmaf(pa.x, inv_eps, LOGW));
      tv1 = fmaf((float)c8[1], nie, fmaf(pa.y, inv_eps, LOGW));
      tv2 = fmaf((float)c8[2], nie, fmaf(pa.z, inv_eps, LOGW));
      tv3 = fmaf((float)c8[3], nie, fmaf(pa.w, inv_eps, LOGW));
      tv4 = fmaf((float)c8[4], nie, fmaf(pb.x, inv_eps, LOGW));
      tv5 = fmaf((float)c8[5], nie, fmaf(pb.y, inv_eps, LOGW));
      tv6 = fmaf((float)c8[6], nie, fmaf(pb.z, inv_eps, LOGW));
      tv7 = fmaf((float)c8[7], nie, fmaf(pb.w, inv_eps, LOGW));
    } else {
      tv0 = fmaf((float)c8[0], nie, LOGW);
      tv1 = fmaf((float)c8[1], nie, LOGW);
      tv2 = fmaf((float)c8[2], nie, LOGW);
      tv3 = fmaf((float)c8[3], nie, LOGW);
      tv4 = fmaf((float)c8[4], nie, LOGW);
      tv5 = fmaf((float)c8[5], nie, LOGW);
      tv6 = fmaf((float)c8[6], nie, LOGW);
      tv7 = fmaf((float)c8[7], nie, LOGW);
    }
    // chunk max (tree, no serial dependence; compiler fuses to v_max3)
    float a01 = fmaxf(tv0, tv1), a23 = fmaxf(tv2, tv3);
    float a45 = fmaxf(tv4, tv5), a67 = fmaxf(tv6, tv7);
    float bm  = fmaxf(fmaxf(a01, a23), fmaxf(a45, a67));
    float mn  = fmaxf(m, bm);
    float e0 = __expf(tv0 - mn), e1 = __expf(tv1 - mn);
    float e2 = __expf(tv2 - mn), e3 = __expf(tv3 - mn);
    float e4 = __expf(tv4 - mn), e5 = __expf(tv5 - mn);
    float e6 = __expf(tv6 - mn), e7 = __expf(tv7 - mn);
    float sum = ((e0 + e1) + (e2 + e3)) + ((e4 + e5) + (e6 + e7));
    s = fmaf(s, __expf(m - mn), sum);   // -inf - mn -> exp = 0 on first iter
    m = mn;
  }
  // wave merge of (m, s)
  #pragma unroll
  for (int o = 1; o < 64; o <<= 1) {
    float m2 = __shfl_xor(m, o, 64);
    float s2 = __shfl_xor(s, o, 64);
    float mn = fmaxf(m, m2);
    s = s * __expf(m - mn) + s2 * __expf(m2 - mn);
    m = mn;
  }
  if (lane == 0) {
    float ft = -eps * (m + __logf(s));
    float v = avg ? 0.5f * (potOld[(size_t)mat * NPTS + row] + ft) : ft;
    potNew[(size_t)mat * NPTS + row] = v;
  }
}

// ---------------------------------------------------------------------------
// out = mean(f_ba - f_aa) + mean(g_ab - g_bb), potentials at pot[0..3][NPTS]
// ---------------------------------------------------------------------------
__global__ __launch_bounds__(256) void final_kernel(
    const float* __restrict__ pot, float* __restrict__ out) {
  __shared__ float red[256];
  float s = 0.0f;
  for (int j = threadIdx.x; j < NPTS; j += 256)
    s += (pot[j] - pot[2 * NPTS + j]) + (pot[NPTS + j] - pot[3 * NPTS + j]);
  red[threadIdx.x] = s;
  __syncthreads();
  #pragma unroll
  for (int o = 128; o; o >>= 1) {
    if (threadIdx.x < o) red[threadIdx.x] += red[threadIdx.x + o];
    __syncthreads();
  }
  if (threadIdx.x == 0) out[0] = red[0] / (float)NPTS;
}

extern "C" void kernel_launch(void* const* d_in, const int* in_sizes, int n_in,
                              void* d_out, int out_size, void* d_ws, size_t ws_size,
                              hipStream_t stream) {
  const float* x = (const float*)d_in[0];
  const float* y = (const float*)d_in[1];
  char* ws = (char*)d_ws;

  // workspace layout
  _Float16* Cw = (_Float16*)ws;                       // 4 * NM fp16 = 128 MB
  __bf16* xh = (__bf16*)(ws + 4 * NM * sizeof(_Float16));
  __bf16* xl = xh + (size_t)NPTS * DIM;
  __bf16* yh = xl + (size_t)NPTS * DIM;
  __bf16* yl = yh + (size_t)NPTS * DIM;
  float* potA = (float*)(yl + (size_t)NPTS * DIM);    // 4 * NPTS
  float* potB = potA + 4 * (size_t)NPTS;
  size_t needed = (size_t)((char*)(potB + 4 * (size_t)NPTS) - ws);
  if (ws_size < needed) return;

  norm_split_kernel<<<2048, 256, 0, stream>>>(x, y, xh, xl, yh, yl);
  cost_mfma_kernel<<<dim3(64, 64, 4), 256, 0, stream>>>(xh, xl, yh, yl, Cw);

  // geomloss epsilon schedule (p=2, blur=0.05, scaling=0.8, diameter=2)
  double lst[32];
  int c = 0;
  lst[c++] = 4.0;
  double start = 2.0 * log(2.0), stop = 2.0 * log(0.05), step = 2.0 * log(0.8);
  for (int k = 0;; ++k) {
    double v = start + (double)k * step;
    if (v <= stop) break;
    lst[c++] = exp(v);
  }
  lst[c++] = 0.05 * 0.05;   // c == 19

  // sweeps: p=0 init (no pot, assign); p=1..c loop (avg); p=c+1 final (assign)
  for (int p = 0; p < c + 2; ++p) {
    double e = (p == 0) ? lst[0] : ((p <= c) ? lst[p - 1] : lst[c - 1]);
    float eps = (float)e;
    float inv_eps = 1.0f / eps;
    int use_pot = (p > 0) ? 1 : 0;
    int avg = (p >= 1 && p <= c) ? 1 : 0;
    const float* po = (p & 1) ? potB : potA;
    float* pn       = (p & 1) ? potA : potB;
    pass_kernel<<<4096, 256, 0, stream>>>(Cw, po, pn, inv_eps, eps, use_pot, avg);
  }
  // c+2 = 21 sweeps; last sweep (p=20, even) wrote potB
  final_kernel<<<1, 256, 0, stream>>>(potB, (float*)d_out);
}